// Round 1
// baseline (294.055 us; speedup 1.0000x reference)
//
#include <hip/hip_runtime.h>
#include <hip/hip_bf16.h>

// SpectralConv3d: closed-form separable transforms (no FFT needed).
// fwd:  X[bc,k1,k2,k3] = sum_{j1,j2,j3} T[k1,j1]T[k2,j2]T[k3,j3] x[bc,j1,j2,j3]
//       T[k,j] = w_j cos(2*pi*j*k/126), w_0=w_63=1 else 2   (k<16, j<64)
// mix:  low[b,o,m] = sum_i X[b,i,m] W[i,o,m]
// inv:  out_re/im = low contracted with cosA (p1), cosA (p2), cosB/sinB (p3)
//       cosA[p,j]=cos(2pi j p/64)/64 (p<33), cosB/sinB[p,j]=cos/sin(2pi j p/33)/33 (p<17)

#define PI2 6.283185307179586476925f

// ---------------- init: transform matrices into workspace ----------------
__global__ void k_init(float* __restrict__ Tmat, float* __restrict__ cA,
                       float* __restrict__ cB, float* __restrict__ sB) {
    int t = blockIdx.x * 256 + threadIdx.x;
    if (t < 1024) {
        int k = t >> 6, j = t & 63;
        float w = (j == 0 || j == 63) ? 1.f : 2.f;
        int r = (j * k) % 126;
        Tmat[t] = w * cosf(PI2 * (float)r / 126.f);
    }
    if (t < 528) {
        int p = t >> 4, j = t & 15;
        int r = (j * p) % 64;
        cA[t] = cosf(PI2 * (float)r / 64.f) * (1.f / 64.f);
    }
    if (t < 272) {
        int p = t >> 4, j = t & 15;
        int r = (j * p) % 33;
        float a = PI2 * (float)r / 33.f;
        cB[t] = cosf(a) * (1.f / 33.f);
        sB[t] = sinf(a) * (1.f / 33.f);
    }
}

// ---------------- fused forward: contract j3 then j2 per (bc, j1) ----------------
// A2[bc][j1][k2][k3] = sum_{j2,j3} x[bc,j1,j2,j3] T[k3,j3] T[k2,j2]
__global__ __launch_bounds__(64) void k_fwd12(const float* __restrict__ x,
                                              const float* __restrict__ Tmat,
                                              float* __restrict__ A2) {
    __shared__ float xt[64 * 68];   // padded stride 68 (17 float4) -> 2-way max
    __shared__ float Ts[16 * 68];
    __shared__ float tmp[16 * 68];  // tmp[k3][j2], padded
    const int j1 = blockIdx.x, bc = blockIdx.y;
    const int t = threadIdx.x;

    float4* xt4 = (float4*)xt;
    float4* Ts4 = (float4*)Ts;
    const float4* xg = (const float4*)(x + ((size_t)bc * 64 + j1) * 4096);
    for (int c = t; c < 1024; c += 64) {
        int j2 = c >> 4, j3q = c & 15;
        xt4[j2 * 17 + j3q] = xg[c];
    }
    const float4* Tg = (const float4*)Tmat;
    for (int c = t; c < 256; c += 64) {
        int k = c >> 4, j3q = c & 15;
        Ts4[k * 17 + j3q] = Tg[c];
    }
    __syncthreads();

    // phase 1: tmp[k3][j2] = sum_j3 xt[j2][j3] * T[k3][j3]
    {
        const int j2b = t & 15;   // j2 = j2b + 16r
        const int k3b = t >> 4;   // k3 = k3b + 4c
        float acc[4][4];
#pragma unroll
        for (int r = 0; r < 4; r++)
#pragma unroll
            for (int c = 0; c < 4; c++) acc[r][c] = 0.f;
#pragma unroll 4
        for (int q = 0; q < 16; q++) {
            float4 xv[4], tv[4];
#pragma unroll
            for (int r = 0; r < 4; r++) xv[r] = xt4[(j2b + 16 * r) * 17 + q];
#pragma unroll
            for (int c = 0; c < 4; c++) tv[c] = Ts4[(k3b + 4 * c) * 17 + q];
#pragma unroll
            for (int r = 0; r < 4; r++)
#pragma unroll
                for (int c = 0; c < 4; c++)
                    acc[r][c] += xv[r].x * tv[c].x + xv[r].y * tv[c].y +
                                 xv[r].z * tv[c].z + xv[r].w * tv[c].w;
        }
#pragma unroll
        for (int r = 0; r < 4; r++)
#pragma unroll
            for (int c = 0; c < 4; c++)
                tmp[(k3b + 4 * c) * 68 + (j2b + 16 * r)] = acc[r][c];
    }
    __syncthreads();

    // phase 2: A2[k2][k3] = sum_j2 tmp[k3][j2] * T[k2][j2]
    {
        const int k3 = t & 15;
        const int k2g = t >> 4;  // k2 = k2g + 4c
        const float4* tmp4 = (const float4*)tmp;
        float acc[4] = {0.f, 0.f, 0.f, 0.f};
#pragma unroll 4
        for (int q = 0; q < 16; q++) {
            float4 tv = tmp4[k3 * 17 + q];
#pragma unroll
            for (int c = 0; c < 4; c++) {
                float4 Tv = Ts4[(k2g + 4 * c) * 17 + q];
                acc[c] += tv.x * Tv.x + tv.y * Tv.y + tv.z * Tv.z + tv.w * Tv.w;
            }
        }
        float* A2p = A2 + ((size_t)bc * 64 + j1) * 256;
#pragma unroll
        for (int c = 0; c < 4; c++)
            A2p[(k2g + 4 * c) * 16 + k3] = acc[c];
    }
}

// ---------------- forward j1 contraction ----------------
// X[bc][k1][m23] = sum_j1 A2[bc][j1][m23] * T[k1][j1]
__global__ __launch_bounds__(256) void k_fwd3(const float* __restrict__ A2,
                                              const float* __restrict__ Tmat,
                                              float* __restrict__ X) {
    __shared__ float Ts[128];
    const int k1g = blockIdx.x;  // 0..7 -> k1 = 2*k1g, 2*k1g+1
    const int bc = blockIdx.y;
    const int t = threadIdx.x;
    if (t < 128) Ts[t] = Tmat[k1g * 128 + t];
    __syncthreads();
    const float* Ap = A2 + (size_t)bc * 64 * 256 + t;
    float a0 = 0.f, a1 = 0.f;
#pragma unroll 8
    for (int j1 = 0; j1 < 64; j1++) {
        float v = Ap[j1 * 256];
        a0 += v * Ts[j1];
        a1 += v * Ts[64 + j1];
    }
    X[(size_t)bc * 4096 + (size_t)(k1g * 2) * 256 + t] = a0;
    X[(size_t)bc * 4096 + (size_t)(k1g * 2 + 1) * 256 + t] = a1;
}

// ---------------- channel mix ----------------
// low[b,o,m] = sum_i X[b*32+i][m] * W[(i*32+o)][m]
__global__ __launch_bounds__(256) void k_mix(const float* __restrict__ X,
                                             const float* __restrict__ W,
                                             float* __restrict__ low) {
    const int mc = blockIdx.x;  // 0..15
    const int o = blockIdx.y;   // 0..31
    const int b = blockIdx.z;   // 0..3
    const int m = mc * 256 + threadIdx.x;
    const float* Xp = X + (size_t)b * 32 * 4096 + m;
    const float* Wp = W + (size_t)o * 4096 + m;
    float acc = 0.f;
#pragma unroll 4
    for (int i = 0; i < 32; i++)
        acc += Xp[(size_t)i * 4096] * Wp[(size_t)i * 32 * 4096];
    low[((size_t)(b * 32 + o)) * 4096 + m] = acc;
}

// ---------------- fused inverse per (bo, p1) ----------------
__global__ __launch_bounds__(256) void k_inv(const float* __restrict__ low,
                                             const float* __restrict__ cA,
                                             const float* __restrict__ cB,
                                             const float* __restrict__ sB,
                                             float* __restrict__ out) {
    __shared__ float lt[4096];
    __shared__ float c1[256];
    __shared__ float c2[528];
    __shared__ float cAs[528], cBs[272], sBs[272];
    const int p1 = blockIdx.x, bo = blockIdx.y;
    const int t = threadIdx.x;

    float4* lt4 = (float4*)lt;
    const float4* lg = (const float4*)(low + (size_t)bo * 4096);
    for (int c = t; c < 1024; c += 256) lt4[c] = lg[c];
    for (int c = t; c < 528; c += 256) cAs[c] = cA[c];
    for (int c = t; c < 272; c += 256) { cBs[c] = cB[c]; sBs[c] = sB[c]; }
    __syncthreads();

    // E: c1[k2*16+k3] = sum_k1 low[k1][k2k3] * cosA[p1][k1]
    {
        float acc = 0.f;
#pragma unroll
        for (int k1 = 0; k1 < 16; k1++) acc += lt[(k1 << 8) + t] * cAs[p1 * 16 + k1];
        c1[t] = acc;
    }
    __syncthreads();

    // F: c2[p2*16+k3] = sum_k2 c1[k2*16+k3] * cosA[p2][k2]
    for (int idx = t; idx < 528; idx += 256) {
        int p2 = idx >> 4, k3 = idx & 15;
        float acc = 0.f;
#pragma unroll
        for (int k2 = 0; k2 < 16; k2++) acc += c1[(k2 << 4) + k3] * cAs[p2 * 16 + k2];
        c2[idx] = acc;
    }
    __syncthreads();

    // G: out[p2][p3][{re,im}] = sum_k3 c2[p2][k3] * cosB/sinB[p3][k3]
    float* op = out + ((size_t)bo * 33 + p1) * 33 * 17 * 2;
    for (int idx = t; idx < 1122; idx += 256) {
        int p2 = idx / 34, rem = idx % 34;
        int p3 = rem >> 1, cc = rem & 1;
        const float* M = cc ? sBs : cBs;
        float acc = 0.f;
#pragma unroll
        for (int k3 = 0; k3 < 16; k3++) acc += c2[(p2 << 4) + k3] * M[p3 * 16 + k3];
        op[idx] = acc;
    }
}

extern "C" void kernel_launch(void* const* d_in, const int* in_sizes, int n_in,
                              void* d_out, int out_size, void* d_ws, size_t ws_size,
                              hipStream_t stream) {
    const float* x = (const float*)d_in[0];   // (4,32,64,64,64)
    const float* W = (const float*)d_in[1];   // (32,32,16,16,16)
    float* out = (float*)d_out;               // (4,32,33,33,17,2)

    float* ws = (float*)d_ws;
    float* Tmat = ws;                 // 1024
    float* cA   = ws + 1024;          // 528
    float* cB   = ws + 1552;          // 272
    float* sB   = ws + 1824;          // 272
    float* A2   = ws + 4096;          // 128*64*256 = 2097152
    float* X    = A2 + 2097152;       // 128*4096   = 524288
    float* low  = X + 524288;         // 128*4096   = 524288

    k_init<<<dim3(4), dim3(256), 0, stream>>>(Tmat, cA, cB, sB);
    k_fwd12<<<dim3(64, 128), dim3(64), 0, stream>>>(x, Tmat, A2);
    k_fwd3<<<dim3(8, 128), dim3(256), 0, stream>>>(A2, Tmat, X);
    k_mix<<<dim3(16, 32, 4), dim3(256), 0, stream>>>(X, W, low);
    k_inv<<<dim3(33, 128), dim3(256), 0, stream>>>(low, cA, cB, sB, out);
}

// Round 2
// 248.181 us; speedup vs baseline: 1.1848x; 1.1848x over previous
//
#include <hip/hip_runtime.h>
#include <hip/hip_bf16.h>

// SpectralConv3d: closed-form separable transforms (no FFT needed).
// fwd:  X[bc,k1,k2,k3] = sum_{j1,j2,j3} T[k1,j1]T[k2,j2]T[k3,j3] x[bc,j1,j2,j3]
//       T[k,j] = w_j cos(2*pi*j*k/126), w_0=w_63=1 else 2   (k<16, j<64)
// mix:  low[b,o,m] = sum_i X[b,i,m] W[i,o,m]
// inv:  out_re/im = low contracted with cosA (p1), cosA (p2), cosB/sinB (p3)
//       cosA[p,j]=cos(2pi j p/64)/64 (p<33), cosB/sinB[p,j]=cos/sin(2pi j p/33)/33 (p<17)

#define PI2 6.283185307179586476925f

// ---------------- init: transform matrices into workspace ----------------
__global__ void k_init(float* __restrict__ Tmat, float* __restrict__ cA,
                       float* __restrict__ cB, float* __restrict__ sB) {
    int t = blockIdx.x * 256 + threadIdx.x;
    if (t < 1024) {
        int k = t >> 6, j = t & 63;
        float w = (j == 0 || j == 63) ? 1.f : 2.f;
        int r = (j * k) % 126;
        Tmat[t] = w * cosf(PI2 * (float)r / 126.f);
    }
    if (t < 528) {
        int p = t >> 4, j = t & 15;
        int r = (j * p) % 64;
        cA[t] = cosf(PI2 * (float)r / 64.f) * (1.f / 64.f);
    }
    if (t < 272) {
        int p = t >> 4, j = t & 15;
        int r = (j * p) % 33;
        float a = PI2 * (float)r / 33.f;
        cB[t] = cosf(a) * (1.f / 33.f);
        sB[t] = sinf(a) * (1.f / 33.f);
    }
}

// ---------------- fused forward: contract j3 then j2 per (bc, j1) ----------------
// A2[bc][j1][k2][k3] = sum_{j2,j3} x[bc,j1,j2,j3] T[k3,j3] T[k2,j2]
// 256 threads (4 waves) per block: occupancy 24 waves/CU (vs 6 at 64 thr).
__global__ __launch_bounds__(256) void k_fwd12(const float* __restrict__ x,
                                               const float* __restrict__ Tmat,
                                               float* __restrict__ A2) {
    __shared__ float xt[64 * 68];   // padded stride 68 (17 float4) -> <=2-way
    __shared__ float Ts[16 * 68];
    __shared__ float tmp[16 * 68];  // tmp[k3][j2], padded
    const int j1 = blockIdx.x, bc = blockIdx.y;
    const int t = threadIdx.x;

    float4* xt4 = (float4*)xt;
    float4* Ts4 = (float4*)Ts;
    const float4* xg = (const float4*)(x + ((size_t)bc * 64 + j1) * 4096);
    for (int c = t; c < 1024; c += 256) {
        int j2 = c >> 4, q = c & 15;
        xt4[j2 * 17 + q] = xg[c];
    }
    if (t < 256) {
        const float4* Tg = (const float4*)Tmat;
        int k = t >> 4, q = t & 15;
        Ts4[k * 17 + q] = Tg[t];
    }
    __syncthreads();

    // phase 1: tmp[k3][j2] = sum_j3 xt[j2][j3] * T[k3][j3]
    // thread: j2 = (t&15) + 16*(t>>6), k3 = ((t>>4)&3) + 4c
    {
        const int j2 = (t & 15) + 16 * (t >> 6);
        const int k3b = (t >> 4) & 3;
        float acc[4] = {0.f, 0.f, 0.f, 0.f};
#pragma unroll 4
        for (int q = 0; q < 16; q++) {
            float4 xv = xt4[j2 * 17 + q];
#pragma unroll
            for (int c = 0; c < 4; c++) {
                float4 tv = Ts4[(k3b + 4 * c) * 17 + q];
                acc[c] += xv.x * tv.x + xv.y * tv.y + xv.z * tv.z + xv.w * tv.w;
            }
        }
#pragma unroll
        for (int c = 0; c < 4; c++)
            tmp[(k3b + 4 * c) * 68 + j2] = acc[c];
    }
    __syncthreads();

    // phase 2: A2[k2][k3] = sum_j2 tmp[k3][j2] * T[k2][j2]
    // thread: k3 = t&15, k2 = t>>4
    {
        const int k3 = t & 15;
        const int k2 = t >> 4;
        const float4* tmp4 = (const float4*)tmp;
        float acc = 0.f;
#pragma unroll 4
        for (int q = 0; q < 16; q++) {
            float4 tv = tmp4[k3 * 17 + q];
            float4 Tv = Ts4[k2 * 17 + q];
            acc += tv.x * Tv.x + tv.y * Tv.y + tv.z * Tv.z + tv.w * Tv.w;
        }
        A2[((size_t)bc * 64 + j1) * 256 + t] = acc;  // k2*16+k3 == t, coalesced
    }
}

// ---------------- forward j1 contraction ----------------
// X[bc][k1][m23] = sum_j1 A2[bc][j1][m23] * T[k1][j1]
__global__ __launch_bounds__(256) void k_fwd3(const float* __restrict__ A2,
                                              const float* __restrict__ Tmat,
                                              float* __restrict__ X) {
    __shared__ float Ts[128];
    const int k1g = blockIdx.x;  // 0..7 -> k1 = 2*k1g, 2*k1g+1
    const int bc = blockIdx.y;
    const int t = threadIdx.x;
    if (t < 128) Ts[t] = Tmat[k1g * 128 + t];
    __syncthreads();
    const float* Ap = A2 + (size_t)bc * 64 * 256 + t;
    float a0 = 0.f, a1 = 0.f;
#pragma unroll 8
    for (int j1 = 0; j1 < 64; j1++) {
        float v = Ap[j1 * 256];
        a0 += v * Ts[j1];
        a1 += v * Ts[64 + j1];
    }
    X[(size_t)bc * 4096 + (size_t)(k1g * 2) * 256 + t] = a0;
    X[(size_t)bc * 4096 + (size_t)(k1g * 2 + 1) * 256 + t] = a1;
}

// ---------------- channel mix ----------------
// low[b,o,m] = sum_i X[b*32+i][m] * W[(i*32+o)][m]
// One block per (m-chunk, o); 4-wide batch accumulator so W is read ONCE.
__global__ __launch_bounds__(256) void k_mix(const float* __restrict__ X,
                                             const float* __restrict__ W,
                                             float* __restrict__ low) {
    const int mc = blockIdx.x;  // 0..15
    const int o = blockIdx.y;   // 0..31
    const int m = mc * 256 + threadIdx.x;
    const float* Xp = X + m;
    const float* Wp = W + (size_t)o * 4096 + m;
    float acc[4] = {0.f, 0.f, 0.f, 0.f};
#pragma unroll 4
    for (int i = 0; i < 32; i++) {
        float wv = Wp[(size_t)i * 32 * 4096];
#pragma unroll
        for (int b = 0; b < 4; b++)
            acc[b] += Xp[(size_t)(b * 32 + i) * 4096] * wv;
    }
#pragma unroll
    for (int b = 0; b < 4; b++)
        low[((size_t)(b * 32 + o)) * 4096 + m] = acc[b];
}

// ---------------- fused inverse per (bo, p1) ----------------
__global__ __launch_bounds__(256) void k_inv(const float* __restrict__ low,
                                             const float* __restrict__ cA,
                                             const float* __restrict__ cB,
                                             const float* __restrict__ sB,
                                             float* __restrict__ out) {
    __shared__ float lt[4096];
    __shared__ float c1[256];
    __shared__ float c2[528];
    __shared__ float cAs[528], cBs[272], sBs[272];
    const int p1 = blockIdx.x, bo = blockIdx.y;
    const int t = threadIdx.x;

    float4* lt4 = (float4*)lt;
    const float4* lg = (const float4*)(low + (size_t)bo * 4096);
    for (int c = t; c < 1024; c += 256) lt4[c] = lg[c];
    for (int c = t; c < 528; c += 256) cAs[c] = cA[c];
    for (int c = t; c < 272; c += 256) { cBs[c] = cB[c]; sBs[c] = sB[c]; }
    __syncthreads();

    // E: c1[k2*16+k3] = sum_k1 low[k1][k2k3] * cosA[p1][k1]
    {
        float acc = 0.f;
#pragma unroll
        for (int k1 = 0; k1 < 16; k1++) acc += lt[(k1 << 8) + t] * cAs[p1 * 16 + k1];
        c1[t] = acc;
    }
    __syncthreads();

    // F: c2[p2*16+k3] = sum_k2 c1[k2*16+k3] * cosA[p2][k2]
    for (int idx = t; idx < 528; idx += 256) {
        int p2 = idx >> 4, k3 = idx & 15;
        float acc = 0.f;
#pragma unroll
        for (int k2 = 0; k2 < 16; k2++) acc += c1[(k2 << 4) + k3] * cAs[p2 * 16 + k2];
        c2[idx] = acc;
    }
    __syncthreads();

    // G: out[p2][p3][{re,im}] = sum_k3 c2[p2][k3] * cosB/sinB[p3][k3]
    float* op = out + ((size_t)bo * 33 + p1) * 33 * 17 * 2;
    for (int idx = t; idx < 1122; idx += 256) {
        int p2 = idx / 34, rem = idx % 34;
        int p3 = rem >> 1, cc = rem & 1;
        const float* M = cc ? sBs : cBs;
        float acc = 0.f;
#pragma unroll
        for (int k3 = 0; k3 < 16; k3++) acc += c2[(p2 << 4) + k3] * M[p3 * 16 + k3];
        op[idx] = acc;
    }
}

extern "C" void kernel_launch(void* const* d_in, const int* in_sizes, int n_in,
                              void* d_out, int out_size, void* d_ws, size_t ws_size,
                              hipStream_t stream) {
    const float* x = (const float*)d_in[0];   // (4,32,64,64,64)
    const float* W = (const float*)d_in[1];   // (32,32,16,16,16)
    float* out = (float*)d_out;               // (4,32,33,33,17,2)

    float* ws = (float*)d_ws;
    float* Tmat = ws;                 // 1024
    float* cA   = ws + 1024;          // 528
    float* cB   = ws + 1552;          // 272
    float* sB   = ws + 1824;          // 272
    float* A2   = ws + 4096;          // 128*64*256 = 2097152
    float* X    = A2 + 2097152;       // 128*4096   = 524288
    float* low  = X + 524288;         // 128*4096   = 524288

    k_init<<<dim3(4), dim3(256), 0, stream>>>(Tmat, cA, cB, sB);
    k_fwd12<<<dim3(64, 128), dim3(256), 0, stream>>>(x, Tmat, A2);
    k_fwd3<<<dim3(8, 128), dim3(256), 0, stream>>>(A2, Tmat, X);
    k_mix<<<dim3(16, 32), dim3(256), 0, stream>>>(X, W, low);
    k_inv<<<dim3(33, 128), dim3(256), 0, stream>>>(low, cA, cB, sB, out);
}